// Round 5
// baseline (789.256 us; speedup 1.0000x reference)
//
#include <hip/hip_runtime.h>

#define TT 4
#define BB 8
#define CC 256
#define NN 512
#define HEADS 16
#define HD 16

#define GLL16(gp, lp) \
    __builtin_amdgcn_global_load_lds( \
        (const __attribute__((address_space(1))) void*)(gp), \
        (__attribute__((address_space(3))) void*)(lp), 16, 0, 0)

struct WPtrs  { const float* w[4]; };
struct BnPtrs { const float* g[4]; const float* b[4]; const float* m[4]; const float* v[4]; };

// -----------------------------------------------------------------------------
// Prep 1: BN affine (sc, bi) per channel. grid(4), block(256).
// -----------------------------------------------------------------------------
__global__ __launch_bounds__(256)
void prep_bn(BnPtrs p, float* __restrict__ sc, float* __restrict__ bi)
{
    int m = blockIdx.x, c = threadIdx.x;
    float rs = __fdiv_rn(1.0f, __fsqrt_rn(__fadd_rn(p.v[m][c], 1e-5f)));
    float s  = __fmul_rn(p.g[m][c], rs);
    sc[m * CC + c] = s;
    bi[m * CC + c] = __fsub_rn(p.b[m][c], __fmul_rn(p.m[m][c], s));
}

// -----------------------------------------------------------------------------
// Prep 2: transpose 4 weight matrices: wt[m][k][o] = w_m[o][k].
// grid(16,16,4), block(16,16).
// -----------------------------------------------------------------------------
__global__ __launch_bounds__(256)
void transpose_w(WPtrs p, float* __restrict__ wt)
{
    __shared__ float t[16][17];
    const int m  = blockIdx.z;
    const float* w = p.w[m];
    const int o0 = blockIdx.y * 16, k0 = blockIdx.x * 16;
    const int tx = threadIdx.x, ty = threadIdx.y;
    t[ty][tx] = w[(size_t)(o0 + ty) * CC + k0 + tx];
    __syncthreads();
    wt[(size_t)m * CC * CC + (size_t)(k0 + ty) * CC + o0 + tx] = t[tx][ty];
}

// -----------------------------------------------------------------------------
// Kernel 1: fused q+k+v conv + BN + LIF(v_th=1) + ballot bit-pack.
// Wave-specialized: wave w owns o-range [o0+8w, o0+8w+8); lanes own n:
// lane l handles n = n0 + j*64 + l (j=0,1). W[k][o] is lane-uniform ->
// s_load to SGPRs (scalar pipe); X staged in LDS via global_load_lds,
// read as 2x ds_read_b32 (imm offsets) per 48 FMAs (3 branches share X).
// grid (4, 8, 8) = 256 blocks; block 256 (4 waves). 2-phase dbuf, BK=32.
// -----------------------------------------------------------------------------
__global__ __launch_bounds__(256)
void qkv_conv_bn_lif_pack(const float* __restrict__ x,     // [T,B,C,N]
                          const float* __restrict__ wt,    // [3][C][C] (k-major)
                          const float* __restrict__ scA,   // [4][C]
                          const float* __restrict__ biA,
                          unsigned long long* __restrict__ bits) // [3][T*B*C*8]
{
    __shared__ float X2[2][32 * 128];   // 2 x 16 KB, [kk][n] rows of 128

    const int tid  = threadIdx.x;
    const int lane = tid & 63;
    const int wv   = __builtin_amdgcn_readfirstlane(tid >> 6); // 0..3, uniform
    const int b  = blockIdx.z;
    const int o0 = blockIdx.y * 32;
    const int n0 = blockIdx.x * 128;
    const int wo0 = o0 + wv * 8;

    // Lane-uniform W bases (one per branch) -> scalar loads.
    const float* w0 = wt + (size_t)0 * CC * CC + wo0;
    const float* w1 = wt + (size_t)1 * CC * CC + wo0;
    const float* w2 = wt + (size_t)2 * CC * CC + wo0;

    float sc[3][8], bi[3][8];
#pragma unroll
    for (int m = 0; m < 3; ++m)
#pragma unroll
        for (int o = 0; o < 8; ++o) {
            sc[m][o] = scA[m * CC + wo0 + o];
            bi[m][o] = biA[m * CC + wo0 + o];
        }

    auto stage = [&](int s, int buf) {
        const int t  = s >> 3;
        const int k0 = (s & 7) * 32;
        const float* xb = x + (size_t)(t * BB + b) * (CC * NN);
#pragma unroll
        for (int i = 0; i < 4; ++i) {
            int idx = tid + 256 * i;          // 0..1023 ; lds byte off = idx*16
            GLL16(&xb[(size_t)(k0 + (idx >> 5)) * NN + n0 + (idx & 31) * 4],
                  &X2[buf][idx * 4]);
        }
    };

    float acc[3][8][2], vst[3][8][2];
#pragma unroll
    for (int m = 0; m < 3; ++m)
#pragma unroll
        for (int o = 0; o < 8; ++o) {
            acc[m][o][0] = 0.0f; acc[m][o][1] = 0.0f;
            vst[m][o][0] = 0.0f; vst[m][o][1] = 0.0f;
        }

    stage(0, 0);
    __syncthreads();

    int cur = 0;
    for (int s = 0; s < 32; ++s) {
        if (s < 31) stage(s + 1, cur ^ 1);

        const int k0 = (s & 7) * 32;
        const float* Xc = &X2[cur][0];
        const float* wr0 = w0 + (size_t)k0 * CC;
        const float* wr1 = w1 + (size_t)k0 * CC;
        const float* wr2 = w2 + (size_t)k0 * CC;

#pragma unroll
        for (int kk = 0; kk < 32; ++kk) {
            float x0 = Xc[kk * 128 + lane];
            float x1 = Xc[kk * 128 + 64 + lane];
#pragma unroll
            for (int o = 0; o < 8; ++o) {
                float a0 = wr0[kk * CC + o];   // lane-uniform -> s_load
                float a1 = wr1[kk * CC + o];
                float a2 = wr2[kk * CC + o];
                acc[0][o][0] = __fmaf_rn(a0, x0, acc[0][o][0]);
                acc[0][o][1] = __fmaf_rn(a0, x1, acc[0][o][1]);
                acc[1][o][0] = __fmaf_rn(a1, x0, acc[1][o][0]);
                acc[1][o][1] = __fmaf_rn(a1, x1, acc[1][o][1]);
                acc[2][o][0] = __fmaf_rn(a2, x0, acc[2][o][0]);
                acc[2][o][1] = __fmaf_rn(a2, x1, acc[2][o][1]);
            }
        }

        if ((s & 7) == 7) {
            const int t = s >> 3;
#pragma unroll
            for (int m = 0; m < 3; ++m) {
                unsigned long long* bout = bits + (size_t)m * (TT * BB * CC * 8);
#pragma unroll
                for (int o = 0; o < 8; ++o) {
                    unsigned long long msk0, msk1;
                    {
                        float ybn = __fadd_rn(__fmul_rn(acc[m][o][0], sc[m][o]), bi[m][o]);
                        float h   = __fadd_rn(vst[m][o][0],
                                              __fmul_rn(__fsub_rn(ybn, vst[m][o][0]), 0.5f));
                        bool sp = (h >= 1.0f);
                        vst[m][o][0] = sp ? 0.0f : h;
                        msk0 = __ballot(sp ? 1 : 0);
                        acc[m][o][0] = 0.0f;
                    }
                    {
                        float ybn = __fadd_rn(__fmul_rn(acc[m][o][1], sc[m][o]), bi[m][o]);
                        float h   = __fadd_rn(vst[m][o][1],
                                              __fmul_rn(__fsub_rn(ybn, vst[m][o][1]), 0.5f));
                        bool sp = (h >= 1.0f);
                        vst[m][o][1] = sp ? 0.0f : h;
                        msk1 = __ballot(sp ? 1 : 0);
                        acc[m][o][1] = 0.0f;
                    }
                    if (lane == 0) {
                        size_t bo = ((size_t)(t * BB + b) * CC + wo0 + o) * 8 + (n0 >> 6);
                        bout[bo + 0] = msk0;
                        bout[bo + 1] = msk1;
                    }
                }
            }
        }

        __syncthreads();
        cur ^= 1;
    }
}

// -----------------------------------------------------------------------------
// Kernel 2: attention via M = K^T V (16x16 integer popcounts), Y = 0.25 * Q M.
// Exact integer arithmetic. grid 512 (tb*16+h), block 256.
// -----------------------------------------------------------------------------
__global__ __launch_bounds__(256)
void attn_kernel(const unsigned long long* __restrict__ bq,
                 const unsigned long long* __restrict__ bk,
                 const unsigned long long* __restrict__ bv,
                 float* __restrict__ y) // [32,C,N]
{
    const int blk = blockIdx.x;
    const int h  = blk & 15;
    const int tb = blk >> 4;
    const int tid = threadIdx.x;

    __shared__ unsigned long long kb[16][8], vb[16][8], qb[16][8];
    __shared__ float M[16][16];

    size_t base = ((size_t)tb * CC + h * HD) * 8;
    if (tid < 128) {
        int j = tid >> 3, ch = tid & 7;
        kb[j][ch] = bk[base + j * 8 + ch];
        vb[j][ch] = bv[base + j * 8 + ch];
        qb[j][ch] = bq[base + j * 8 + ch];
    }
    __syncthreads();

    {
        int j = tid >> 4, d = tid & 15;
        int cnt = 0;
#pragma unroll
        for (int ch = 0; ch < 8; ++ch)
            cnt += __popcll(kb[j][ch] & vb[d][ch]);
        M[j][d] = (float)cnt;
    }
    __syncthreads();

    size_t ybase = ((size_t)tb * CC + h * HD) * (size_t)NN;
#pragma unroll
    for (int r = 0; r < 2; ++r) {
        int n = tid + 256 * r;
        int ch = n >> 6, sh = n & 63;
        float acc[16];
#pragma unroll
        for (int d = 0; d < 16; ++d) acc[d] = 0.0f;
#pragma unroll
        for (int j = 0; j < 16; ++j) {
            float bit = (float)((qb[j][ch] >> sh) & 1ULL);
#pragma unroll
            for (int d = 0; d < 16; ++d)
                acc[d] = __fmaf_rn(bit, M[j][d], acc[d]);
        }
#pragma unroll
        for (int d = 0; d < 16; ++d)
            y[ybase + (size_t)d * NN + n] = __fmul_rn(acc[d], 0.25f);
    }
}

// -----------------------------------------------------------------------------
// Kernel 3: attn LIF (v_th=0.5) in-place on y, spikes stored as 1.0f/0.0f.
// grid 512, block 256.
// -----------------------------------------------------------------------------
__global__ __launch_bounds__(256)
void attn_lif(float* __restrict__ y)
{
    const int e = blockIdx.x * 256 + threadIdx.x; // < 131072
    float xs[32];
#pragma unroll
    for (int tb = 0; tb < 32; ++tb)
        xs[tb] = y[(size_t)tb * (CC * NN) + e];
    float v = 0.0f;
#pragma unroll
    for (int tb = 0; tb < 32; ++tb) {
        float h = __fadd_rn(v, __fmul_rn(__fsub_rn(xs[tb], v), 0.5f));
        bool sp = (h >= 0.5f);
        y[(size_t)tb * (CC * NN) + e] = sp ? 1.0f : 0.0f;
        v = sp ? 0.0f : h;
    }
}

// -----------------------------------------------------------------------------
// Kernel 4: proj conv on float spikes + BN + final LIF(v_th=1), f32 out.
// Same wave-specialized scalar-W template, single branch.
// grid (4, 8, 8) = 256 blocks; block 256 (4 waves).
// -----------------------------------------------------------------------------
__global__ __launch_bounds__(256)
void proj_bn_lif(const float* __restrict__ sfl, // [32,C,N] float spikes
                 const float* __restrict__ wt3, // [C][C] k-major (proj)
                 const float* __restrict__ scA,
                 const float* __restrict__ biA,
                 float* __restrict__ out)
{
    __shared__ float X2[2][32 * 128];

    const int tid  = threadIdx.x;
    const int lane = tid & 63;
    const int wv   = __builtin_amdgcn_readfirstlane(tid >> 6);
    const int b  = blockIdx.z;
    const int o0 = blockIdx.y * 32;
    const int n0 = blockIdx.x * 128;
    const int wo0 = o0 + wv * 8;

    const float* w0 = wt3 + wo0;

    float sc[8], bi[8];
#pragma unroll
    for (int o = 0; o < 8; ++o) {
        sc[o] = scA[3 * CC + wo0 + o];
        bi[o] = biA[3 * CC + wo0 + o];
    }

    auto stage = [&](int s, int buf) {
        const int t  = s >> 3;
        const int k0 = (s & 7) * 32;
        const float* xb = sfl + (size_t)(t * BB + b) * (CC * NN);
#pragma unroll
        for (int i = 0; i < 4; ++i) {
            int idx = tid + 256 * i;
            GLL16(&xb[(size_t)(k0 + (idx >> 5)) * NN + n0 + (idx & 31) * 4],
                  &X2[buf][idx * 4]);
        }
    };

    float acc[8][2], vst[8][2];
#pragma unroll
    for (int o = 0; o < 8; ++o) {
        acc[o][0] = 0.0f; acc[o][1] = 0.0f;
        vst[o][0] = 0.0f; vst[o][1] = 0.0f;
    }

    stage(0, 0);
    __syncthreads();

    int cur = 0;
    for (int s = 0; s < 32; ++s) {
        if (s < 31) stage(s + 1, cur ^ 1);

        const int k0 = (s & 7) * 32;
        const float* Xc = &X2[cur][0];
        const float* wr = w0 + (size_t)k0 * CC;

#pragma unroll
        for (int kk = 0; kk < 32; ++kk) {
            float x0 = Xc[kk * 128 + lane];
            float x1 = Xc[kk * 128 + 64 + lane];
#pragma unroll
            for (int o = 0; o < 8; ++o) {
                float a = wr[kk * CC + o];    // lane-uniform -> s_load
                acc[o][0] = __fmaf_rn(a, x0, acc[o][0]);
                acc[o][1] = __fmaf_rn(a, x1, acc[o][1]);
            }
        }

        if ((s & 7) == 7) {
            const int t = s >> 3;
#pragma unroll
            for (int o = 0; o < 8; ++o) {
#pragma unroll
                for (int j = 0; j < 2; ++j) {
                    float ybn = __fadd_rn(__fmul_rn(acc[o][j], sc[o]), bi[o]);
                    float h   = __fadd_rn(vst[o][j],
                                          __fmul_rn(__fsub_rn(ybn, vst[o][j]), 0.5f));
                    bool sp = (h >= 1.0f);
                    vst[o][j] = sp ? 0.0f : h;
                    acc[o][j] = 0.0f;
                    out[((size_t)(t * BB + b) * CC + wo0 + o) * NN + n0 + j * 64 + lane]
                        = sp ? 1.0f : 0.0f;
                }
            }
        }

        __syncthreads();
        cur ^= 1;
    }
}

// -----------------------------------------------------------------------------
extern "C" void kernel_launch(void* const* d_in, const int* in_sizes, int n_in,
                              void* d_out, int out_size, void* d_ws, size_t ws_size,
                              hipStream_t stream) {
    const float* x = (const float*)d_in[0];

    WPtrs wp;
    BnPtrs bp;
    for (int m = 0; m < 4; ++m) {
        wp.w[m] = (const float*)d_in[1 + m * 5 + 0];
        bp.g[m] = (const float*)d_in[1 + m * 5 + 1];
        bp.b[m] = (const float*)d_in[1 + m * 5 + 2];
        bp.m[m] = (const float*)d_in[1 + m * 5 + 3];
        bp.v[m] = (const float*)d_in[1 + m * 5 + 4];
    }

    char* ws = (char*)d_ws;
    float* wt   = (float*)ws;                                    // 1 MB
    float* scA  = (float*)(ws + (1u << 20));                     // 4 KB
    float* biA  = (float*)(ws + (1u << 20) + 4096);              // 4 KB
    unsigned long long* bits = (unsigned long long*)(ws + (1u << 20) + 8192); // 1.5 MB
    float* ybuf = (float*)(ws + (1u << 20) + 8192 + (1536u << 10));           // 16 MB

    prep_bn<<<4, 256, 0, stream>>>(bp, scA, biA);
    transpose_w<<<dim3(16, 16, 4), dim3(16, 16), 0, stream>>>(wp, wt);

    qkv_conv_bn_lif_pack<<<dim3(4, 8, 8), 256, 0, stream>>>(x, wt, scA, biA, bits);

    const unsigned long long* bq = bits;
    const unsigned long long* bk = bits + 65536;
    const unsigned long long* bv = bits + 131072;
    attn_kernel<<<512, 256, 0, stream>>>(bq, bk, bv, ybuf);
    attn_lif<<<512, 256, 0, stream>>>(ybuf);
    proj_bn_lif<<<dim3(4, 8, 8), 256, 0, stream>>>(ybuf, wt + 3 * CC * CC, scA, biA, (float*)d_out);
}

// Round 8
// 297.339 us; speedup vs baseline: 2.6544x; 2.6544x over previous
//
#include <hip/hip_runtime.h>

#define TT 4
#define BB 8
#define CC 256
#define NN 512
#define HEADS 16
#define HD 16

#define GLL16(gp, lp) \
    __builtin_amdgcn_global_load_lds( \
        (const __attribute__((address_space(1))) void*)(gp), \
        (__attribute__((address_space(3))) void*)(lp), 16, 0, 0)

struct WPtrs  { const float* w[4]; };
struct BnPtrs { const float* g[4]; const float* b[4]; const float* m[4]; const float* v[4]; };

// -----------------------------------------------------------------------------
// Prep 1: BN affine (sc, bi) per channel. grid(4), block(256).
// -----------------------------------------------------------------------------
__global__ __launch_bounds__(256)
void prep_bn(BnPtrs p, float* __restrict__ sc, float* __restrict__ bi)
{
    int m = blockIdx.x, c = threadIdx.x;
    float rs = __fdiv_rn(1.0f, __fsqrt_rn(__fadd_rn(p.v[m][c], 1e-5f)));
    float s  = __fmul_rn(p.g[m][c], rs);
    sc[m * CC + c] = s;
    bi[m * CC + c] = __fsub_rn(p.b[m][c], __fmul_rn(p.m[m][c], s));
}

// -----------------------------------------------------------------------------
// Prep 2: transpose 4 weight matrices: wt[m][k][o] = w_m[o][k].
// grid(16,16,4), block(16,16).
// -----------------------------------------------------------------------------
__global__ __launch_bounds__(256)
void transpose_w(WPtrs p, float* __restrict__ wt)
{
    __shared__ float t[16][17];
    const int m  = blockIdx.z;
    const float* w = p.w[m];
    const int o0 = blockIdx.y * 16, k0 = blockIdx.x * 16;
    const int tx = threadIdx.x, ty = threadIdx.y;
    t[ty][tx] = w[(size_t)(o0 + ty) * CC + k0 + tx];
    __syncthreads();
    wt[(size_t)m * CC * CC + (size_t)(k0 + ty) * CC + o0 + tx] = t[tx][ty];
}

// -----------------------------------------------------------------------------
// Kernel 1: fused q/k/v conv + BN + LIF(v_th=1) + bit-pack, t-loop inside.
// 128(o) x 128(n) block tiles, 8x8 per thread (16x16 threads, 4 waves).
// W and X both in LDS (b128 reads; W reads are 16-way broadcast).
// 32 stages = 4t x 8 k-tiles (BK=32), 2-phase double buffer.
// grid (4, 2, 24): z = br*8 + b. LDS 66 KB. Spike pack via LDS byte transpose.
// -----------------------------------------------------------------------------
__global__ __launch_bounds__(256)
void qkv_conv_bn_lif_pack(const float* __restrict__ x,     // [T,B,C,N]
                          const float* __restrict__ wt,    // [3][C][C] (k-major)
                          const float* __restrict__ scA,   // [4][C]
                          const float* __restrict__ biA,
                          unsigned long long* __restrict__ bits) // [3][T*B*C*8]
{
    __shared__ float Wl[2][32][128];        // 2 x 16 KB [k][o]
    __shared__ float Xl[2][32][128];        // 2 x 16 KB [k][n]
    __shared__ unsigned char Spk[128][16];  // 2 KB

    const int tid = threadIdx.x;
    const int tx = tid & 15;
    const int ty = tid >> 4;
    const int br = blockIdx.z >> 3;
    const int b  = blockIdx.z & 7;
    const int o0 = blockIdx.y * 128;
    const int n0 = blockIdx.x * 128;

    const float* wb = wt + (size_t)br * CC * CC;
    unsigned long long* bout = bits + (size_t)br * (TT * BB * CC * 8);

    float sc[8], bi[8];
#pragma unroll
    for (int i = 0; i < 8; ++i) {
        sc[i] = scA[br * CC + o0 + ty * 8 + i];
        bi[i] = biA[br * CC + o0 + ty * 8 + i];
    }

    auto stage = [&](int s, int buf) {
        const int t  = s >> 3;
        const int k0 = (s & 7) * 32;
        const float* xb = x + (size_t)(t * BB + b) * (CC * NN);
#pragma unroll
        for (int i = 0; i < 4; ++i) {
            int idx = tid + 256 * i;      // 0..1023 ; LDS linear at idx*16
            int row = idx >> 5, cg = idx & 31;
            GLL16(&wb[(size_t)(k0 + row) * CC + o0 + cg * 4], &Wl[buf][row][cg * 4]);
        }
#pragma unroll
        for (int i = 0; i < 4; ++i) {
            int idx = tid + 256 * i;
            int row = idx >> 5, cg = idx & 31;
            GLL16(&xb[(size_t)(k0 + row) * NN + n0 + cg * 4], &Xl[buf][row][cg * 4]);
        }
    };

    float acc[8][8], vst[8][8];
#pragma unroll
    for (int i = 0; i < 8; ++i)
#pragma unroll
        for (int j = 0; j < 8; ++j) { acc[i][j] = 0.0f; vst[i][j] = 0.0f; }

    stage(0, 0);
    __syncthreads();

    int cur = 0;
    for (int s = 0; s < 32; ++s) {
        if (s < 31) stage(s + 1, cur ^ 1);

#pragma unroll 8
        for (int kk = 0; kk < 32; ++kk) {
            const float4 w0 = *reinterpret_cast<const float4*>(&Wl[cur][kk][ty * 8]);
            const float4 w1 = *reinterpret_cast<const float4*>(&Wl[cur][kk][ty * 8 + 4]);
            const float4 x0 = *reinterpret_cast<const float4*>(&Xl[cur][kk][tx * 8]);
            const float4 x1 = *reinterpret_cast<const float4*>(&Xl[cur][kk][tx * 8 + 4]);
            const float wa[8] = {w0.x, w0.y, w0.z, w0.w, w1.x, w1.y, w1.z, w1.w};
            const float xa[8] = {x0.x, x0.y, x0.z, x0.w, x1.x, x1.y, x1.z, x1.w};
#pragma unroll
            for (int i = 0; i < 8; ++i)
#pragma unroll
                for (int j = 0; j < 8; ++j)
                    acc[i][j] = __fmaf_rn(wa[i], xa[j], acc[i][j]);
        }

        if ((s & 7) == 7) {
            const int t = s >> 3;
#pragma unroll
            for (int i = 0; i < 8; ++i) {
                unsigned int byte = 0u;
#pragma unroll
                for (int j = 0; j < 8; ++j) {
                    float ybn = __fadd_rn(__fmul_rn(acc[i][j], sc[i]), bi[i]);
                    float h   = __fadd_rn(vst[i][j],
                                          __fmul_rn(__fsub_rn(ybn, vst[i][j]), 0.5f));
                    bool sp = (h >= 1.0f);
                    vst[i][j] = sp ? 0.0f : h;
                    byte |= (sp ? 1u : 0u) << j;
                    acc[i][j] = 0.0f;
                }
                Spk[ty * 8 + i][tx] = (unsigned char)byte;
            }
            __syncthreads();
            {
                int o = tid >> 1, ch = tid & 1;
                unsigned long long m =
                    *reinterpret_cast<const unsigned long long*>(&Spk[o][ch * 8]);
                bout[((size_t)(t * BB + b) * CC + o0 + o) * 8 + (blockIdx.x * 2 + ch)] = m;
            }
        }

        __syncthreads();
        cur ^= 1;
    }
}

// -----------------------------------------------------------------------------
// Kernel 2: attention via M = K^T V (16x16 integer popcounts), Y = 0.25 * Q M.
// Exact integer arithmetic. grid 512 (tb*16+h), block 256.
// -----------------------------------------------------------------------------
__global__ __launch_bounds__(256)
void attn_kernel(const unsigned long long* __restrict__ bq,
                 const unsigned long long* __restrict__ bk,
                 const unsigned long long* __restrict__ bv,
                 float* __restrict__ y) // [32,C,N]
{
    const int blk = blockIdx.x;
    const int h  = blk & 15;
    const int tb = blk >> 4;
    const int tid = threadIdx.x;

    __shared__ unsigned long long kb[16][8], vb[16][8], qb[16][8];
    __shared__ float M[16][16];

    size_t base = ((size_t)tb * CC + h * HD) * 8;
    if (tid < 128) {
        int j = tid >> 3, ch = tid & 7;
        kb[j][ch] = bk[base + j * 8 + ch];
        vb[j][ch] = bv[base + j * 8 + ch];
        qb[j][ch] = bq[base + j * 8 + ch];
    }
    __syncthreads();

    {
        int j = tid >> 4, d = tid & 15;
        int cnt = 0;
#pragma unroll
        for (int ch = 0; ch < 8; ++ch)
            cnt += __popcll(kb[j][ch] & vb[d][ch]);
        M[j][d] = (float)cnt;
    }
    __syncthreads();

    size_t ybase = ((size_t)tb * CC + h * HD) * (size_t)NN;
#pragma unroll
    for (int r = 0; r < 2; ++r) {
        int n = tid + 256 * r;
        int ch = n >> 6, sh = n & 63;
        float acc[16];
#pragma unroll
        for (int d = 0; d < 16; ++d) acc[d] = 0.0f;
#pragma unroll
        for (int j = 0; j < 16; ++j) {
            float bit = (float)((qb[j][ch] >> sh) & 1ULL);
#pragma unroll
            for (int d = 0; d < 16; ++d)
                acc[d] = __fmaf_rn(bit, M[j][d], acc[d]);
        }
#pragma unroll
        for (int d = 0; d < 16; ++d)
            y[ybase + (size_t)d * NN + n] = __fmul_rn(acc[d], 0.25f);
    }
}

// -----------------------------------------------------------------------------
// Kernel 3: attn LIF (v_th=0.5) in-place on y, spikes stored as 1.0f/0.0f.
// grid 512, block 256: one (c,n) chain of 32 steps per thread.
// -----------------------------------------------------------------------------
__global__ __launch_bounds__(256)
void attn_lif(float* __restrict__ y)
{
    const int e = blockIdx.x * 256 + threadIdx.x; // < 131072
    float xs[32];
#pragma unroll
    for (int tb = 0; tb < 32; ++tb)
        xs[tb] = y[(size_t)tb * (CC * NN) + e];
    float v = 0.0f;
#pragma unroll
    for (int tb = 0; tb < 32; ++tb) {
        float h = __fadd_rn(v, __fmul_rn(__fsub_rn(xs[tb], v), 0.5f));
        bool sp = (h >= 0.5f);
        y[(size_t)tb * (CC * NN) + e] = sp ? 1.0f : 0.0f;
        v = sp ? 0.0f : h;
    }
}

// -----------------------------------------------------------------------------
// Kernel 4: proj conv + BN, t-parallel (LIF decoupled). 128x128 tiles, 8x8
// per thread, BK=32 double-buffered. grid (4, 2, 32): z = tb. Writes BN'd
// pre-activations (f32) to ybn_p.
// -----------------------------------------------------------------------------
__global__ __launch_bounds__(256)
void proj_gemm_bn(const float* __restrict__ X,   // [32][C][N] float spikes
                  const float* __restrict__ wtp, // [C][C] k-major (proj)
                  const float* __restrict__ scP, // [C] (pre-offset)
                  const float* __restrict__ biP,
                  float* __restrict__ Y)         // [32][C][N]
{
    __shared__ float Wl[2][32][128];
    __shared__ float Xl[2][32][128];

    const int tid = threadIdx.x;
    const int tx = tid & 15;
    const int ty = tid >> 4;
    const int tb = blockIdx.z;
    const int o0 = blockIdx.y * 128;
    const int n0 = blockIdx.x * 128;

    const float* xb = X + (size_t)tb * (CC * NN);

    float sc[8], bi[8];
#pragma unroll
    for (int i = 0; i < 8; ++i) {
        sc[i] = scP[o0 + ty * 8 + i];
        bi[i] = biP[o0 + ty * 8 + i];
    }

    auto stage = [&](int s, int buf) {
        const int k0 = s * 32;
#pragma unroll
        for (int i = 0; i < 4; ++i) {
            int idx = tid + 256 * i;
            int row = idx >> 5, cg = idx & 31;
            GLL16(&wtp[(size_t)(k0 + row) * CC + o0 + cg * 4], &Wl[buf][row][cg * 4]);
        }
#pragma unroll
        for (int i = 0; i < 4; ++i) {
            int idx = tid + 256 * i;
            int row = idx >> 5, cg = idx & 31;
            GLL16(&xb[(size_t)(k0 + row) * NN + n0 + cg * 4], &Xl[buf][row][cg * 4]);
        }
    };

    float acc[8][8];
#pragma unroll
    for (int i = 0; i < 8; ++i)
#pragma unroll
        for (int j = 0; j < 8; ++j) acc[i][j] = 0.0f;

    stage(0, 0);
    __syncthreads();

    int cur = 0;
    for (int s = 0; s < 8; ++s) {
        if (s < 7) stage(s + 1, cur ^ 1);

#pragma unroll 8
        for (int kk = 0; kk < 32; ++kk) {
            const float4 w0 = *reinterpret_cast<const float4*>(&Wl[cur][kk][ty * 8]);
            const float4 w1 = *reinterpret_cast<const float4*>(&Wl[cur][kk][ty * 8 + 4]);
            const float4 x0 = *reinterpret_cast<const float4*>(&Xl[cur][kk][tx * 8]);
            const float4 x1 = *reinterpret_cast<const float4*>(&Xl[cur][kk][tx * 8 + 4]);
            const float wa[8] = {w0.x, w0.y, w0.z, w0.w, w1.x, w1.y, w1.z, w1.w};
            const float xa[8] = {x0.x, x0.y, x0.z, x0.w, x1.x, x1.y, x1.z, x1.w};
#pragma unroll
            for (int i = 0; i < 8; ++i)
#pragma unroll
                for (int j = 0; j < 8; ++j)
                    acc[i][j] = __fmaf_rn(wa[i], xa[j], acc[i][j]);
        }

        __syncthreads();
        cur ^= 1;
    }

    float* Yp = Y + (size_t)tb * (CC * NN);
#pragma unroll
    for (int i = 0; i < 8; ++i) {
        float r[8];
#pragma unroll
        for (int j = 0; j < 8; ++j)
            r[j] = __fadd_rn(__fmul_rn(acc[i][j], sc[i]), bi[i]);
        float4 r0 = make_float4(r[0], r[1], r[2], r[3]);
        float4 r1 = make_float4(r[4], r[5], r[6], r[7]);
        float* dst = &Yp[(size_t)(o0 + ty * 8 + i) * NN + n0 + tx * 8];
        *reinterpret_cast<float4*>(dst) = r0;
        *reinterpret_cast<float4*>(dst + 4) = r1;
    }
}

// -----------------------------------------------------------------------------
// Kernel 5: final LIF(v_th=1) over T=4, float4-vectorized, writes 1.0f/0.0f.
// grid 1024, block 256: each thread owns 4 consecutive elements of [B,C,N].
// -----------------------------------------------------------------------------
__global__ __launch_bounds__(256)
void final_lif(const float* __restrict__ Yp, float* __restrict__ out)
{
    const size_t stride = (size_t)BB * CC * NN;     // 1048576
    const int i4 = blockIdx.x * 256 + threadIdx.x;  // < 262144
    float4 v = make_float4(0.f, 0.f, 0.f, 0.f);
#pragma unroll
    for (int t = 0; t < 4; ++t) {
        float4 xv = *reinterpret_cast<const float4*>(&Yp[t * stride + (size_t)i4 * 4]);
        float4 o4;
        float h;
        h = __fadd_rn(v.x, __fmul_rn(__fsub_rn(xv.x, v.x), 0.5f));
        o4.x = (h >= 1.0f) ? 1.0f : 0.0f; v.x = (h >= 1.0f) ? 0.0f : h;
        h = __fadd_rn(v.y, __fmul_rn(__fsub_rn(xv.y, v.y), 0.5f));
        o4.y = (h >= 1.0f) ? 1.0f : 0.0f; v.y = (h >= 1.0f) ? 0.0f : h;
        h = __fadd_rn(v.z, __fmul_rn(__fsub_rn(xv.z, v.z), 0.5f));
        o4.z = (h >= 1.0f) ? 1.0f : 0.0f; v.z = (h >= 1.0f) ? 0.0f : h;
        h = __fadd_rn(v.w, __fmul_rn(__fsub_rn(xv.w, v.w), 0.5f));
        o4.w = (h >= 1.0f) ? 1.0f : 0.0f; v.w = (h >= 1.0f) ? 0.0f : h;
        *reinterpret_cast<float4*>(&out[t * stride + (size_t)i4 * 4]) = o4;
    }
}

// -----------------------------------------------------------------------------
extern "C" void kernel_launch(void* const* d_in, const int* in_sizes, int n_in,
                              void* d_out, int out_size, void* d_ws, size_t ws_size,
                              hipStream_t stream) {
    const float* x = (const float*)d_in[0];

    WPtrs wp;
    BnPtrs bp;
    for (int m = 0; m < 4; ++m) {
        wp.w[m] = (const float*)d_in[1 + m * 5 + 0];
        bp.g[m] = (const float*)d_in[1 + m * 5 + 1];
        bp.b[m] = (const float*)d_in[1 + m * 5 + 2];
        bp.m[m] = (const float*)d_in[1 + m * 5 + 3];
        bp.v[m] = (const float*)d_in[1 + m * 5 + 4];
    }

    char* ws = (char*)d_ws;
    float* wt   = (float*)ws;                                     // 1 MB
    float* scA  = (float*)(ws + (1u << 20));                      // 4 KB
    float* biA  = (float*)(ws + (1u << 20) + 4096);               // 4 KB
    unsigned long long* bits = (unsigned long long*)(ws + (1u << 20) + 8192); // 1.5 MB
    float* ybuf  = (float*)(ws + (1u << 20) + 8192 + 1572864);    // 16 MB
    float* ybn_p = (float*)(ws + (1u << 20) + 8192 + 1572864 + 16777216); // 16 MB

    prep_bn<<<4, 256, 0, stream>>>(bp, scA, biA);
    transpose_w<<<dim3(16, 16, 4), dim3(16, 16), 0, stream>>>(wp, wt);

    qkv_conv_bn_lif_pack<<<dim3(4, 2, 24), 256, 0, stream>>>(x, wt, scA, biA, bits);

    const unsigned long long* bq = bits;
    const unsigned long long* bk = bits + 65536;
    const unsigned long long* bv = bits + 131072;
    attn_kernel<<<512, 256, 0, stream>>>(bq, bk, bv, ybuf);
    attn_lif<<<512, 256, 0, stream>>>(ybuf);

    proj_gemm_bn<<<dim3(4, 2, 32), 256, 0, stream>>>(
        ybuf, wt + 3 * CC * CC, scA + 3 * CC, biA + 3 * CC, ybn_p);
    final_lif<<<1024, 256, 0, stream>>>(ybn_p, (float*)d_out);
}

// Round 9
// 287.703 us; speedup vs baseline: 2.7433x; 1.0335x over previous
//
#include <hip/hip_runtime.h>

#define TT 4
#define BB 8
#define CC 256
#define NN 512
#define HEADS 16
#define HD 16

#define GLL16(gp, lp) \
    __builtin_amdgcn_global_load_lds( \
        (const __attribute__((address_space(1))) void*)(gp), \
        (__attribute__((address_space(3))) void*)(lp), 16, 0, 0)

struct WPtrs  { const float* w[4]; };
struct BnPtrs { const float* g[4]; const float* b[4]; const float* m[4]; const float* v[4]; };

// -----------------------------------------------------------------------------
// Prep 1: BN affine (sc, bi) per channel. grid(4), block(256).
// -----------------------------------------------------------------------------
__global__ __launch_bounds__(256)
void prep_bn(BnPtrs p, float* __restrict__ sc, float* __restrict__ bi)
{
    int m = blockIdx.x, c = threadIdx.x;
    float rs = __fdiv_rn(1.0f, __fsqrt_rn(__fadd_rn(p.v[m][c], 1e-5f)));
    float s  = __fmul_rn(p.g[m][c], rs);
    sc[m * CC + c] = s;
    bi[m * CC + c] = __fsub_rn(p.b[m][c], __fmul_rn(p.m[m][c], s));
}

// -----------------------------------------------------------------------------
// Prep 2: transpose 4 weight matrices: wt[m][k][o] = w_m[o][k].
// grid(16,16,4), block(16,16).
// -----------------------------------------------------------------------------
__global__ __launch_bounds__(256)
void transpose_w(WPtrs p, float* __restrict__ wt)
{
    __shared__ float t[16][17];
    const int m  = blockIdx.z;
    const float* w = p.w[m];
    const int o0 = blockIdx.y * 16, k0 = blockIdx.x * 16;
    const int tx = threadIdx.x, ty = threadIdx.y;
    t[ty][tx] = w[(size_t)(o0 + ty) * CC + k0 + tx];
    __syncthreads();
    wt[(size_t)m * CC * CC + (size_t)(k0 + ty) * CC + o0 + tx] = t[tx][ty];
}

// -----------------------------------------------------------------------------
// Kernel 1: fused q/k/v conv + BN + LIF(v_th=1) + bit-pack. ONE WAVE per block.
// 64(o) x 64(n) tiles, 8x8 per thread (tx=lane&7 n-octet, ty=lane>>3 o-octet).
// Both ds_read_b128 streams have 8 distinct addrs/wave -> 2-way alias = free.
// 32 stages = 4t x 8 k-tiles (BK=32), 2-phase dbuf. LDS 32.5 KB.
// grid (8, 4, 24) = 768 blocks = exactly 3 blocks/CU.
// -----------------------------------------------------------------------------
__global__ __launch_bounds__(64)
void qkv_conv_bn_lif_pack(const float* __restrict__ x,     // [T,B,C,N]
                          const float* __restrict__ wt,    // [3][C][C] (k-major)
                          const float* __restrict__ scA,   // [4][C]
                          const float* __restrict__ biA,
                          unsigned long long* __restrict__ bits) // [3][T*B*C*8]
{
    __shared__ float Wl[2][32][64];       // 2 x 8 KB [k][o]
    __shared__ float Xl[2][32][64];       // 2 x 8 KB [k][n]
    __shared__ unsigned char Spk[64][8];  // 512 B

    const int lane = threadIdx.x;   // 0..63
    const int tx = lane & 7;
    const int ty = lane >> 3;
    const int br = blockIdx.z >> 3;
    const int b  = blockIdx.z & 7;
    const int o0 = blockIdx.y * 64;
    const int n0 = blockIdx.x * 64;

    const float* wb = wt + (size_t)br * CC * CC;
    unsigned long long* bout = bits + (size_t)br * (TT * BB * CC * 8);

    float sc[8], bi[8];
#pragma unroll
    for (int i = 0; i < 8; ++i) {
        sc[i] = scA[br * CC + o0 + ty * 8 + i];
        bi[i] = biA[br * CC + o0 + ty * 8 + i];
    }

    auto stage = [&](int s, int buf) {
        const int t  = s >> 3;
        const int k0 = (s & 7) * 32;
        const float* xb = x + (size_t)(t * BB + b) * (CC * NN);
#pragma unroll
        for (int i = 0; i < 8; ++i) {
            int idx = lane + 64 * i;          // 0..511 ; LDS linear at idx*16
            int row = idx >> 4, cg = idx & 15;
            GLL16(&wb[(size_t)(k0 + row) * CC + o0 + cg * 4], &Wl[buf][row][cg * 4]);
            GLL16(&xb[(size_t)(k0 + row) * NN + n0 + cg * 4], &Xl[buf][row][cg * 4]);
        }
    };

    float acc[8][8], vst[8][8];
#pragma unroll
    for (int i = 0; i < 8; ++i)
#pragma unroll
        for (int j = 0; j < 8; ++j) { acc[i][j] = 0.0f; vst[i][j] = 0.0f; }

    stage(0, 0);
    __syncthreads();

    int cur = 0;
    for (int s = 0; s < 32; ++s) {
        if (s < 31) stage(s + 1, cur ^ 1);

#pragma unroll 8
        for (int kk = 0; kk < 32; ++kk) {
            const float4 w0 = *reinterpret_cast<const float4*>(&Wl[cur][kk][ty * 8]);
            const float4 w1 = *reinterpret_cast<const float4*>(&Wl[cur][kk][ty * 8 + 4]);
            const float4 x0 = *reinterpret_cast<const float4*>(&Xl[cur][kk][tx * 8]);
            const float4 x1 = *reinterpret_cast<const float4*>(&Xl[cur][kk][tx * 8 + 4]);
            const float wa[8] = {w0.x, w0.y, w0.z, w0.w, w1.x, w1.y, w1.z, w1.w};
            const float xa[8] = {x0.x, x0.y, x0.z, x0.w, x1.x, x1.y, x1.z, x1.w};
#pragma unroll
            for (int i = 0; i < 8; ++i)
#pragma unroll
                for (int j = 0; j < 8; ++j)
                    acc[i][j] = __fmaf_rn(wa[i], xa[j], acc[i][j]);
        }

        if ((s & 7) == 7) {
            const int t = s >> 3;
#pragma unroll
            for (int i = 0; i < 8; ++i) {
                unsigned int byte = 0u;
#pragma unroll
                for (int j = 0; j < 8; ++j) {
                    float ybn = __fadd_rn(__fmul_rn(acc[i][j], sc[i]), bi[i]);
                    float h   = __fadd_rn(vst[i][j],
                                          __fmul_rn(__fsub_rn(ybn, vst[i][j]), 0.5f));
                    bool sp = (h >= 1.0f);
                    vst[i][j] = sp ? 0.0f : h;
                    byte |= (sp ? 1u : 0u) << j;
                    acc[i][j] = 0.0f;
                }
                Spk[ty * 8 + i][tx] = (unsigned char)byte;
            }
            __syncthreads();
            {
                unsigned long long m =
                    *reinterpret_cast<const unsigned long long*>(&Spk[lane][0]);
                bout[((size_t)(t * BB + b) * CC + o0 + lane) * 8 + (n0 >> 6)] = m;
            }
        }

        __syncthreads();
        cur ^= 1;
    }
}

// -----------------------------------------------------------------------------
// Kernel 2: attention via M = K^T V (16x16 integer popcounts), Y = 0.25 * Q M.
// Exact integer arithmetic. grid 512 (tb*16+h), block 256.
// -----------------------------------------------------------------------------
__global__ __launch_bounds__(256)
void attn_kernel(const unsigned long long* __restrict__ bq,
                 const unsigned long long* __restrict__ bk,
                 const unsigned long long* __restrict__ bv,
                 float* __restrict__ y) // [32,C,N]
{
    const int blk = blockIdx.x;
    const int h  = blk & 15;
    const int tb = blk >> 4;
    const int tid = threadIdx.x;

    __shared__ unsigned long long kb[16][8], vb[16][8], qb[16][8];
    __shared__ float M[16][16];

    size_t base = ((size_t)tb * CC + h * HD) * 8;
    if (tid < 128) {
        int j = tid >> 3, ch = tid & 7;
        kb[j][ch] = bk[base + j * 8 + ch];
        vb[j][ch] = bv[base + j * 8 + ch];
        qb[j][ch] = bq[base + j * 8 + ch];
    }
    __syncthreads();

    {
        int j = tid >> 4, d = tid & 15;
        int cnt = 0;
#pragma unroll
        for (int ch = 0; ch < 8; ++ch)
            cnt += __popcll(kb[j][ch] & vb[d][ch]);
        M[j][d] = (float)cnt;
    }
    __syncthreads();

    size_t ybase = ((size_t)tb * CC + h * HD) * (size_t)NN;
#pragma unroll
    for (int r = 0; r < 2; ++r) {
        int n = tid + 256 * r;
        int ch = n >> 6, sh = n & 63;
        float acc[16];
#pragma unroll
        for (int d = 0; d < 16; ++d) acc[d] = 0.0f;
#pragma unroll
        for (int j = 0; j < 16; ++j) {
            float bit = (float)((qb[j][ch] >> sh) & 1ULL);
#pragma unroll
            for (int d = 0; d < 16; ++d)
                acc[d] = __fmaf_rn(bit, M[j][d], acc[d]);
        }
#pragma unroll
        for (int d = 0; d < 16; ++d)
            y[ybase + (size_t)d * NN + n] = __fmul_rn(acc[d], 0.25f);
    }
}

// -----------------------------------------------------------------------------
// Kernel 3: attn LIF (v_th=0.5) in-place on y, spikes stored as 1.0f/0.0f.
// grid 512, block 256: one (c,n) chain of 32 steps per thread.
// -----------------------------------------------------------------------------
__global__ __launch_bounds__(256)
void attn_lif(float* __restrict__ y)
{
    const int e = blockIdx.x * 256 + threadIdx.x; // < 131072
    float xs[32];
#pragma unroll
    for (int tb = 0; tb < 32; ++tb)
        xs[tb] = y[(size_t)tb * (CC * NN) + e];
    float v = 0.0f;
#pragma unroll
    for (int tb = 0; tb < 32; ++tb) {
        float h = __fadd_rn(v, __fmul_rn(__fsub_rn(xs[tb], v), 0.5f));
        bool sp = (h >= 0.5f);
        y[(size_t)tb * (CC * NN) + e] = sp ? 1.0f : 0.0f;
        v = sp ? 0.0f : h;
    }
}

// -----------------------------------------------------------------------------
// Kernel 4: proj conv + BN, t-parallel, ONE WAVE per block. 64x64 tiles,
// 8x8 per thread, BK=32 dbuf. grid (8, 4, 32) = 1024 blocks = 4/CU.
// Writes BN'd pre-activations (f32) to ybn_p.
// -----------------------------------------------------------------------------
__global__ __launch_bounds__(64)
void proj_gemm_bn(const float* __restrict__ X,   // [32][C][N] float spikes
                  const float* __restrict__ wtp, // [C][C] k-major (proj)
                  const float* __restrict__ scP, // [C] (pre-offset)
                  const float* __restrict__ biP,
                  float* __restrict__ Y)         // [32][C][N]
{
    __shared__ float Wl[2][32][64];
    __shared__ float Xl[2][32][64];

    const int lane = threadIdx.x;
    const int tx = lane & 7;
    const int ty = lane >> 3;
    const int tb = blockIdx.z;
    const int o0 = blockIdx.y * 64;
    const int n0 = blockIdx.x * 64;

    const float* xb = X + (size_t)tb * (CC * NN);

    float sc[8], bi[8];
#pragma unroll
    for (int i = 0; i < 8; ++i) {
        sc[i] = scP[o0 + ty * 8 + i];
        bi[i] = biP[o0 + ty * 8 + i];
    }

    auto stage = [&](int s, int buf) {
        const int k0 = s * 32;
#pragma unroll
        for (int i = 0; i < 8; ++i) {
            int idx = lane + 64 * i;
            int row = idx >> 4, cg = idx & 15;
            GLL16(&wtp[(size_t)(k0 + row) * CC + o0 + cg * 4], &Wl[buf][row][cg * 4]);
            GLL16(&xb [(size_t)(k0 + row) * NN + n0 + cg * 4], &Xl[buf][row][cg * 4]);
        }
    };

    float acc[8][8];
#pragma unroll
    for (int i = 0; i < 8; ++i)
#pragma unroll
        for (int j = 0; j < 8; ++j) acc[i][j] = 0.0f;

    stage(0, 0);
    __syncthreads();

    int cur = 0;
    for (int s = 0; s < 8; ++s) {
        if (s < 7) stage(s + 1, cur ^ 1);

#pragma unroll 8
        for (int kk = 0; kk < 32; ++kk) {
            const float4 w0 = *reinterpret_cast<const float4*>(&Wl[cur][kk][ty * 8]);
            const float4 w1 = *reinterpret_cast<const float4*>(&Wl[cur][kk][ty * 8 + 4]);
            const float4 x0 = *reinterpret_cast<const float4*>(&Xl[cur][kk][tx * 8]);
            const float4 x1 = *reinterpret_cast<const float4*>(&Xl[cur][kk][tx * 8 + 4]);
            const float wa[8] = {w0.x, w0.y, w0.z, w0.w, w1.x, w1.y, w1.z, w1.w};
            const float xa[8] = {x0.x, x0.y, x0.z, x0.w, x1.x, x1.y, x1.z, x1.w};
#pragma unroll
            for (int i = 0; i < 8; ++i)
#pragma unroll
                for (int j = 0; j < 8; ++j)
                    acc[i][j] = __fmaf_rn(wa[i], xa[j], acc[i][j]);
        }

        __syncthreads();
        cur ^= 1;
    }

    float* Yp = Y + (size_t)tb * (CC * NN);
#pragma unroll
    for (int i = 0; i < 8; ++i) {
        float r[8];
#pragma unroll
        for (int j = 0; j < 8; ++j)
            r[j] = __fadd_rn(__fmul_rn(acc[i][j], sc[i]), bi[i]);
        float4 r0 = make_float4(r[0], r[1], r[2], r[3]);
        float4 r1 = make_float4(r[4], r[5], r[6], r[7]);
        float* dst = &Yp[(size_t)(o0 + ty * 8 + i) * NN + n0 + tx * 8];
        *reinterpret_cast<float4*>(dst) = r0;
        *reinterpret_cast<float4*>(dst + 4) = r1;
    }
}

// -----------------------------------------------------------------------------
// Kernel 5: final LIF(v_th=1) over T=4, float4-vectorized, writes 1.0f/0.0f.
// grid 1024, block 256: each thread owns 4 consecutive elements of [B,C,N].
// -----------------------------------------------------------------------------
__global__ __launch_bounds__(256)
void final_lif(const float* __restrict__ Yp, float* __restrict__ out)
{
    const size_t stride = (size_t)BB * CC * NN;     // 1048576
    const int i4 = blockIdx.x * 256 + threadIdx.x;  // < 262144
    float4 v = make_float4(0.f, 0.f, 0.f, 0.f);
#pragma unroll
    for (int t = 0; t < 4; ++t) {
        float4 xv = *reinterpret_cast<const float4*>(&Yp[t * stride + (size_t)i4 * 4]);
        float4 o4;
        float h;
        h = __fadd_rn(v.x, __fmul_rn(__fsub_rn(xv.x, v.x), 0.5f));
        o4.x = (h >= 1.0f) ? 1.0f : 0.0f; v.x = (h >= 1.0f) ? 0.0f : h;
        h = __fadd_rn(v.y, __fmul_rn(__fsub_rn(xv.y, v.y), 0.5f));
        o4.y = (h >= 1.0f) ? 1.0f : 0.0f; v.y = (h >= 1.0f) ? 0.0f : h;
        h = __fadd_rn(v.z, __fmul_rn(__fsub_rn(xv.z, v.z), 0.5f));
        o4.z = (h >= 1.0f) ? 1.0f : 0.0f; v.z = (h >= 1.0f) ? 0.0f : h;
        h = __fadd_rn(v.w, __fmul_rn(__fsub_rn(xv.w, v.w), 0.5f));
        o4.w = (h >= 1.0f) ? 1.0f : 0.0f; v.w = (h >= 1.0f) ? 0.0f : h;
        *reinterpret_cast<float4*>(&out[t * stride + (size_t)i4 * 4]) = o4;
    }
}

// -----------------------------------------------------------------------------
extern "C" void kernel_launch(void* const* d_in, const int* in_sizes, int n_in,
                              void* d_out, int out_size, void* d_ws, size_t ws_size,
                              hipStream_t stream) {
    const float* x = (const float*)d_in[0];

    WPtrs wp;
    BnPtrs bp;
    for (int m = 0; m < 4; ++m) {
        wp.w[m] = (const float*)d_in[1 + m * 5 + 0];
        bp.g[m] = (const float*)d_in[1 + m * 5 + 1];
        bp.b[m] = (const float*)d_in[1 + m * 5 + 2];
        bp.m[m] = (const float*)d_in[1 + m * 5 + 3];
        bp.v[m] = (const float*)d_in[1 + m * 5 + 4];
    }

    char* ws = (char*)d_ws;
    float* wt   = (float*)ws;                                     // 1 MB
    float* scA  = (float*)(ws + (1u << 20));                      // 4 KB
    float* biA  = (float*)(ws + (1u << 20) + 4096);               // 4 KB
    unsigned long long* bits = (unsigned long long*)(ws + (1u << 20) + 8192); // 1.5 MB
    float* ybuf  = (float*)(ws + (1u << 20) + 8192 + 1572864);    // 16 MB
    float* ybn_p = (float*)(ws + (1u << 20) + 8192 + 1572864 + 16777216); // 16 MB

    prep_bn<<<4, 256, 0, stream>>>(bp, scA, biA);
    transpose_w<<<dim3(16, 16, 4), dim3(16, 16), 0, stream>>>(wp, wt);

    qkv_conv_bn_lif_pack<<<dim3(8, 4, 24), 64, 0, stream>>>(x, wt, scA, biA, bits);

    const unsigned long long* bq = bits;
    const unsigned long long* bk = bits + 65536;
    const unsigned long long* bv = bits + 131072;
    attn_kernel<<<512, 256, 0, stream>>>(bq, bk, bv, ybuf);
    attn_lif<<<512, 256, 0, stream>>>(ybuf);

    proj_gemm_bn<<<dim3(8, 4, 32), 64, 0, stream>>>(
        ybuf, wt + 3 * CC * CC, scA + 3 * CC, biA + 3 * CC, ybn_p);
    final_lif<<<1024, 256, 0, stream>>>(ybn_p, (float*)d_out);
}

// Round 10
// 251.464 us; speedup vs baseline: 3.1386x; 1.1441x over previous
//
#include <hip/hip_runtime.h>

#define TT 4
#define BB 8
#define CC 256
#define NN 512
#define HEADS 16
#define HD 16

#define GLL16(gp, lp) \
    __builtin_amdgcn_global_load_lds( \
        (const __attribute__((address_space(1))) void*)(gp), \
        (__attribute__((address_space(3))) void*)(lp), 16, 0, 0)

struct WPtrs  { const float* w[4]; };
struct BnPtrs { const float* g[4]; const float* b[4]; const float* m[4]; const float* v[4]; };

// -----------------------------------------------------------------------------
// Prep 1: BN affine (sc, bi) per channel. grid(4), block(256).
// -----------------------------------------------------------------------------
__global__ __launch_bounds__(256)
void prep_bn(BnPtrs p, float* __restrict__ sc, float* __restrict__ bi)
{
    int m = blockIdx.x, c = threadIdx.x;
    float rs = __fdiv_rn(1.0f, __fsqrt_rn(__fadd_rn(p.v[m][c], 1e-5f)));
    float s  = __fmul_rn(p.g[m][c], rs);
    sc[m * CC + c] = s;
    bi[m * CC + c] = __fsub_rn(p.b[m][c], __fmul_rn(p.m[m][c], s));
}

// -----------------------------------------------------------------------------
// Prep 2: transpose 4 weight matrices: wt[m][k][o] = w_m[o][k].
// grid(16,16,4), block(16,16).
// -----------------------------------------------------------------------------
__global__ __launch_bounds__(256)
void transpose_w(WPtrs p, float* __restrict__ wt)
{
    __shared__ float t[16][17];
    const int m  = blockIdx.z;
    const float* w = p.w[m];
    const int o0 = blockIdx.y * 16, k0 = blockIdx.x * 16;
    const int tx = threadIdx.x, ty = threadIdx.y;
    t[ty][tx] = w[(size_t)(o0 + ty) * CC + k0 + tx];
    __syncthreads();
    wt[(size_t)m * CC * CC + (size_t)(k0 + ty) * CC + o0 + tx] = t[tx][ty];
}

// -----------------------------------------------------------------------------
// Kernel A: q/k/v conv + BN, T-PARALLEL (LIF decoupled). 128x128 tiles,
// 256 threads = 4 waves in 2x2 wave-quadrants of 64x64; 8x8 per thread.
// All LDS reads have 8 distinct addresses per wave (2-way alias = free).
// BK=32, 8 stages, double-buffered; LDS 64 KB -> 2 blocks/CU, 8 waves/CU;
// grid (4, 2, 96): z = br*32 + tb -> 768 blocks = 12 waves/CU time-avg.
// Writes BN'd pre-activations ybn3[br][tb][c][n] (f32).
// -----------------------------------------------------------------------------
__global__ __launch_bounds__(256)
void qkv_gemm_bn(const float* __restrict__ x,     // [32][C][N]
                 const float* __restrict__ wt,    // [3][C][C] k-major
                 const float* __restrict__ scA,   // [4][C]
                 const float* __restrict__ biA,
                 float* __restrict__ ybn3)        // [3][32][C][N]
{
    __shared__ float Wl[2][32][128];   // 32 KB [k][o]
    __shared__ float Xl[2][32][128];   // 32 KB [k][n]

    const int tid  = threadIdx.x;
    const int wave = tid >> 6;
    const int lane = tid & 63;
    const int wr = wave >> 1;          // o-quadrant
    const int wc = wave & 1;           // n-quadrant
    const int ty = lane >> 3;          // 8 o-rows of 8
    const int tx = lane & 7;           // 8 n-cols of 8
    const int br = blockIdx.z >> 5;
    const int tb = blockIdx.z & 31;
    const int o0 = blockIdx.y * 128;
    const int n0 = blockIdx.x * 128;
    const int oo = o0 + wr * 64 + ty * 8;   // thread's first o
    const int nn = n0 + wc * 64 + tx * 8;   // thread's first n

    const float* wb = wt + (size_t)br * CC * CC;
    const float* xb = x + (size_t)tb * (CC * NN);

    auto stage = [&](int s, int buf) {
        const int k0 = s * 32;
#pragma unroll
        for (int i = 0; i < 4; ++i) {
            int idx = tid + 256 * i;          // 0..1023 ; LDS linear at idx*16
            int row = idx >> 5, cg = idx & 31;
            GLL16(&wb[(size_t)(k0 + row) * CC + o0 + cg * 4], &Wl[buf][row][cg * 4]);
        }
#pragma unroll
        for (int i = 0; i < 4; ++i) {
            int idx = tid + 256 * i;
            int row = idx >> 5, cg = idx & 31;
            GLL16(&xb[(size_t)(k0 + row) * NN + n0 + cg * 4], &Xl[buf][row][cg * 4]);
        }
    };

    float acc[8][8];
#pragma unroll
    for (int i = 0; i < 8; ++i)
#pragma unroll
        for (int j = 0; j < 8; ++j) acc[i][j] = 0.0f;

    stage(0, 0);
    __syncthreads();

    int cur = 0;
    for (int s = 0; s < 8; ++s) {
        if (s < 7) stage(s + 1, cur ^ 1);

#pragma unroll 8
        for (int kk = 0; kk < 32; ++kk) {
            const float4 w0 = *reinterpret_cast<const float4*>(&Wl[cur][kk][wr * 64 + ty * 8]);
            const float4 w1 = *reinterpret_cast<const float4*>(&Wl[cur][kk][wr * 64 + ty * 8 + 4]);
            const float4 x0 = *reinterpret_cast<const float4*>(&Xl[cur][kk][wc * 64 + tx * 8]);
            const float4 x1 = *reinterpret_cast<const float4*>(&Xl[cur][kk][wc * 64 + tx * 8 + 4]);
            const float wa[8] = {w0.x, w0.y, w0.z, w0.w, w1.x, w1.y, w1.z, w1.w};
            const float xa[8] = {x0.x, x0.y, x0.z, x0.w, x1.x, x1.y, x1.z, x1.w};
#pragma unroll
            for (int i = 0; i < 8; ++i)
#pragma unroll
                for (int j = 0; j < 8; ++j)
                    acc[i][j] = __fmaf_rn(wa[i], xa[j], acc[i][j]);
        }

        __syncthreads();
        cur ^= 1;
    }

    float* Yp = ybn3 + ((size_t)br * 32 + tb) * (CC * NN);
#pragma unroll
    for (int i = 0; i < 8; ++i) {
        const float sc = scA[br * CC + oo + i];
        const float bi = biA[br * CC + oo + i];
        float r[8];
#pragma unroll
        for (int j = 0; j < 8; ++j)
            r[j] = __fadd_rn(__fmul_rn(acc[i][j], sc), bi);
        float* dst = &Yp[(size_t)(oo + i) * NN + nn];
        *reinterpret_cast<float4*>(dst)     = make_float4(r[0], r[1], r[2], r[3]);
        *reinterpret_cast<float4*>(dst + 4) = make_float4(r[4], r[5], r[6], r[7]);
    }
}

// -----------------------------------------------------------------------------
// Kernel B: q/k/v LIF(v_th=1) over T=4 + ballot bit-pack.
// grid 12288 x 256: thread g -> (br, b, c, n); lanes = 64 consecutive n.
// -----------------------------------------------------------------------------
__global__ __launch_bounds__(256)
void qkv_lif_pack(const float* __restrict__ ybn3,      // [3][32][C][N]
                  unsigned long long* __restrict__ bits) // [3][32*C*8]
{
    const int g = blockIdx.x * 256 + threadIdx.x;
    const int n = g & 511;
    const int c = (g >> 9) & 255;
    const int b = (g >> 17) & 7;
    const int br = g >> 20;

    const float* src = ybn3 + (size_t)br * 32 * (CC * NN);
    unsigned long long* bout = bits + (size_t)br * (32 * CC * 8);

    float v = 0.0f;
#pragma unroll
    for (int t = 0; t < 4; ++t) {
        const int tb = t * 8 + b;
        float xv = src[((size_t)tb * CC + c) * NN + n];
        float h  = __fadd_rn(v, __fmul_rn(__fsub_rn(xv, v), 0.5f));
        bool sp = (h >= 1.0f);
        v = sp ? 0.0f : h;
        unsigned long long msk = __ballot(sp ? 1 : 0);
        if ((threadIdx.x & 63) == 0)
            bout[((size_t)tb * CC + c) * 8 + (n >> 6)] = msk;
    }
}

// -----------------------------------------------------------------------------
// Kernel 2: attention via M = K^T V (16x16 integer popcounts), Y = 0.25 * Q M.
// Exact integer arithmetic. grid 512 (tb*16+h), block 256.
// -----------------------------------------------------------------------------
__global__ __launch_bounds__(256)
void attn_kernel(const unsigned long long* __restrict__ bq,
                 const unsigned long long* __restrict__ bk,
                 const unsigned long long* __restrict__ bv,
                 float* __restrict__ y) // [32,C,N]
{
    const int blk = blockIdx.x;
    const int h  = blk & 15;
    const int tb = blk >> 4;
    const int tid = threadIdx.x;

    __shared__ unsigned long long kb[16][8], vb[16][8], qb[16][8];
    __shared__ float M[16][16];

    size_t base = ((size_t)tb * CC + h * HD) * 8;
    if (tid < 128) {
        int j = tid >> 3, ch = tid & 7;
        kb[j][ch] = bk[base + j * 8 + ch];
        vb[j][ch] = bv[base + j * 8 + ch];
        qb[j][ch] = bq[base + j * 8 + ch];
    }
    __syncthreads();

    {
        int j = tid >> 4, d = tid & 15;
        int cnt = 0;
#pragma unroll
        for (int ch = 0; ch < 8; ++ch)
            cnt += __popcll(kb[j][ch] & vb[d][ch]);
        M[j][d] = (float)cnt;
    }
    __syncthreads();

    size_t ybase = ((size_t)tb * CC + h * HD) * (size_t)NN;
#pragma unroll
    for (int r = 0; r < 2; ++r) {
        int n = tid + 256 * r;
        int ch = n >> 6, sh = n & 63;
        float acc[16];
#pragma unroll
        for (int d = 0; d < 16; ++d) acc[d] = 0.0f;
#pragma unroll
        for (int j = 0; j < 16; ++j) {
            float bit = (float)((qb[j][ch] >> sh) & 1ULL);
#pragma unroll
            for (int d = 0; d < 16; ++d)
                acc[d] = __fmaf_rn(bit, M[j][d], acc[d]);
        }
#pragma unroll
        for (int d = 0; d < 16; ++d)
            y[ybase + (size_t)d * NN + n] = __fmul_rn(acc[d], 0.25f);
    }
}

// -----------------------------------------------------------------------------
// Kernel 3: attn LIF (v_th=0.5) in-place on y, spikes stored as 1.0f/0.0f.
// grid 512, block 256: one (c,n) chain of 32 steps per thread.
// -----------------------------------------------------------------------------
__global__ __launch_bounds__(256)
void attn_lif(float* __restrict__ y)
{
    const int e = blockIdx.x * 256 + threadIdx.x; // < 131072
    float xs[32];
#pragma unroll
    for (int tb = 0; tb < 32; ++tb)
        xs[tb] = y[(size_t)tb * (CC * NN) + e];
    float v = 0.0f;
#pragma unroll
    for (int tb = 0; tb < 32; ++tb) {
        float h = __fadd_rn(v, __fmul_rn(__fsub_rn(xs[tb], v), 0.5f));
        bool sp = (h >= 0.5f);
        y[(size_t)tb * (CC * NN) + e] = sp ? 1.0f : 0.0f;
        v = sp ? 0.0f : h;
    }
}

// -----------------------------------------------------------------------------
// Kernel 4: proj conv + BN, t-parallel. 128(o) x 64(n) tiles, 256 threads,
// 8x4 per thread (ty=tid>>4 o-octet, tx=tid&15 n-quad). BK=32 dbuf, LDS 48KB.
// grid (8, 2, 32) = 512 blocks = 2/CU = 8 waves/CU.
// -----------------------------------------------------------------------------
__global__ __launch_bounds__(256)
void proj_gemm_bn(const float* __restrict__ X,   // [32][C][N] float spikes
                  const float* __restrict__ wtp, // [C][C] k-major (proj)
                  const float* __restrict__ scP, // [C]
                  const float* __restrict__ biP,
                  float* __restrict__ Y)         // [32][C][N]
{
    __shared__ float Wl[2][32][128];  // 32 KB
    __shared__ float Xl[2][32][64];   // 16 KB

    const int tid = threadIdx.x;
    const int tx = tid & 15;
    const int ty = tid >> 4;
    const int tb = blockIdx.z;
    const int o0 = blockIdx.y * 128;
    const int n0 = blockIdx.x * 64;

    const float* xb = X + (size_t)tb * (CC * NN);

    auto stage = [&](int s, int buf) {
        const int k0 = s * 32;
#pragma unroll
        for (int i = 0; i < 4; ++i) {
            int idx = tid + 256 * i;
            int row = idx >> 5, cg = idx & 31;
            GLL16(&wtp[(size_t)(k0 + row) * CC + o0 + cg * 4], &Wl[buf][row][cg * 4]);
        }
#pragma unroll
        for (int i = 0; i < 2; ++i) {
            int idx = tid + 256 * i;          // 0..511
            int row = idx >> 4, cg = idx & 15;
            GLL16(&xb[(size_t)(k0 + row) * NN + n0 + cg * 4], &Xl[buf][row][cg * 4]);
        }
    };

    float acc[8][4];
#pragma unroll
    for (int i = 0; i < 8; ++i)
#pragma unroll
        for (int j = 0; j < 4; ++j) acc[i][j] = 0.0f;

    stage(0, 0);
    __syncthreads();

    int cur = 0;
    for (int s = 0; s < 8; ++s) {
        if (s < 7) stage(s + 1, cur ^ 1);

#pragma unroll 8
        for (int kk = 0; kk < 32; ++kk) {
            const float4 w0 = *reinterpret_cast<const float4*>(&Wl[cur][kk][ty * 8]);
            const float4 w1 = *reinterpret_cast<const float4*>(&Wl[cur][kk][ty * 8 + 4]);
            const float4 xv = *reinterpret_cast<const float4*>(&Xl[cur][kk][tx * 4]);
            const float wa[8] = {w0.x, w0.y, w0.z, w0.w, w1.x, w1.y, w1.z, w1.w};
            const float xa[4] = {xv.x, xv.y, xv.z, xv.w};
#pragma unroll
            for (int i = 0; i < 8; ++i)
#pragma unroll
                for (int j = 0; j < 4; ++j)
                    acc[i][j] = __fmaf_rn(wa[i], xa[j], acc[i][j]);
        }

        __syncthreads();
        cur ^= 1;
    }

    float* Yp = Y + (size_t)tb * (CC * NN);
#pragma unroll
    for (int i = 0; i < 8; ++i) {
        const float sc = scP[o0 + ty * 8 + i];
        const float bi = biP[o0 + ty * 8 + i];
        float r[4];
#pragma unroll
        for (int j = 0; j < 4; ++j)
            r[j] = __fadd_rn(__fmul_rn(acc[i][j], sc), bi);
        *reinterpret_cast<float4*>(&Yp[(size_t)(o0 + ty * 8 + i) * NN + n0 + tx * 4])
            = make_float4(r[0], r[1], r[2], r[3]);
    }
}

// -----------------------------------------------------------------------------
// Kernel 5: final LIF(v_th=1) over T=4, float4-vectorized, writes 1.0f/0.0f.
// grid 1024, block 256.
// -----------------------------------------------------------------------------
__global__ __launch_bounds__(256)
void final_lif(const float* __restrict__ Yp, float* __restrict__ out)
{
    const size_t stride = (size_t)BB * CC * NN;     // 1048576
    const int i4 = blockIdx.x * 256 + threadIdx.x;  // < 262144
    float4 v = make_float4(0.f, 0.f, 0.f, 0.f);
#pragma unroll
    for (int t = 0; t < 4; ++t) {
        float4 xv = *reinterpret_cast<const float4*>(&Yp[t * stride + (size_t)i4 * 4]);
        float4 o4;
        float h;
        h = __fadd_rn(v.x, __fmul_rn(__fsub_rn(xv.x, v.x), 0.5f));
        o4.x = (h >= 1.0f) ? 1.0f : 0.0f; v.x = (h >= 1.0f) ? 0.0f : h;
        h = __fadd_rn(v.y, __fmul_rn(__fsub_rn(xv.y, v.y), 0.5f));
        o4.y = (h >= 1.0f) ? 1.0f : 0.0f; v.y = (h >= 1.0f) ? 0.0f : h;
        h = __fadd_rn(v.z, __fmul_rn(__fsub_rn(xv.z, v.z), 0.5f));
        o4.z = (h >= 1.0f) ? 1.0f : 0.0f; v.z = (h >= 1.0f) ? 0.0f : h;
        h = __fadd_rn(v.w, __fmul_rn(__fsub_rn(xv.w, v.w), 0.5f));
        o4.w = (h >= 1.0f) ? 1.0f : 0.0f; v.w = (h >= 1.0f) ? 0.0f : h;
        *reinterpret_cast<float4*>(&out[t * stride + (size_t)i4 * 4]) = o4;
    }
}

// -----------------------------------------------------------------------------
extern "C" void kernel_launch(void* const* d_in, const int* in_sizes, int n_in,
                              void* d_out, int out_size, void* d_ws, size_t ws_size,
                              hipStream_t stream) {
    const float* x = (const float*)d_in[0];

    WPtrs wp;
    BnPtrs bp;
    for (int m = 0; m < 4; ++m) {
        wp.w[m] = (const float*)d_in[1 + m * 5 + 0];
        bp.g[m] = (const float*)d_in[1 + m * 5 + 1];
        bp.b[m] = (const float*)d_in[1 + m * 5 + 2];
        bp.m[m] = (const float*)d_in[1 + m * 5 + 3];
        bp.v[m] = (const float*)d_in[1 + m * 5 + 4];
    }

    // Workspace layout (~50.6 MB):
    //   wt 1 MB | scA 4 KB | biA 4 KB | bits 1.5 MB | big 48 MB
    //   big: ybn3 [3][32][C][N] f32 (48 MB), dead after qkv_lif_pack;
    //        then ybuf (attn, 16 MB) aliases big+0 and ybn_p aliases big+16MB.
    char* ws = (char*)d_ws;
    float* wt   = (float*)ws;
    float* scA  = (float*)(ws + (1u << 20));
    float* biA  = (float*)(ws + (1u << 20) + 4096);
    unsigned long long* bits = (unsigned long long*)(ws + (1u << 20) + 8192);
    char*  big  = ws + (1u << 20) + 8192 + 1572864;
    float* ybn3 = (float*)big;                       // 48 MB
    float* ybuf = (float*)big;                       // 16 MB (after ybn3 dead)
    float* ybn_p = (float*)(big + (16u << 20));      // 16 MB

    prep_bn<<<4, 256, 0, stream>>>(bp, scA, biA);
    transpose_w<<<dim3(16, 16, 4), dim3(16, 16), 0, stream>>>(wp, wt);

    qkv_gemm_bn<<<dim3(4, 2, 96), 256, 0, stream>>>(x, wt, scA, biA, ybn3);
    qkv_lif_pack<<<12288, 256, 0, stream>>>(ybn3, bits);

    const unsigned long long* bq = bits;
    const unsigned long long* bk = bits + 65536;
    const unsigned long long* bv = bits + 131072;
    attn_kernel<<<512, 256, 0, stream>>>(bq, bk, bv, ybuf);
    attn_lif<<<512, 256, 0, stream>>>(ybuf);

    proj_gemm_bn<<<dim3(8, 2, 32), 256, 0, stream>>>(
        ybuf, wt + 3 * CC * CC, scA + 3 * CC, biA + 3 * CC, ybn_p);
    final_lif<<<1024, 256, 0, stream>>>(ybn_p, (float*)d_out);
}